// Round 8
// baseline (109.553 us; speedup 1.0000x reference)
//
#include <hip/hip_runtime.h>
#include <hip/hip_bf16.h>
#include <stdint.h>

typedef __attribute__((ext_vector_type(8))) __bf16 bf16x8;
typedef __attribute__((ext_vector_type(4))) float f32x4;

#define N_PTS 1600
#define HD    64

// ---- ws layout (bytes). R20: same as R19 (3-kernel chain, smooth-X before proj).
#define OFF_WT   0u          //  393216 : 3 x [256][256] bf16 W^T
#define OFF_BIAS 393216u     //    1536 : 3 x 256 bf16
#define OFF_XS   394752u     //  819200 : [1600][256] bf16 smoothed canonical x
#define OFF_QH   1213952u    //  819200 : [4][1600][64] bf16 Q (live through attn)
#define OFF_KF   2033152u    //  819200 : fragment-major K  [kg][50 t][4 ch][64 lane][8]
#define OFF_VF   2852352u    //  819200 : fragment-major smoothed V [vg][50 t][4 ds][64 lane][8]

__device__ __forceinline__ float bf2f(ushort h) {
  union { uint32_t u; float f; } v; v.u = ((uint32_t)h) << 16; return v.f;
}
__device__ __forceinline__ ushort f2bf(float f) {
  union { float f; uint32_t u; } v; v.f = f;
  uint32_t u = v.u;
  return (ushort)((u + 0x7FFFu + ((u >> 16) & 1u)) >> 16);
}
__device__ __forceinline__ uint32_t pk2(float a, float b) {
  union { __hip_bfloat162 h; uint32_t u; } cv;
  cv.h = __float22bfloat162_rn(make_float2(a, b));
  return cv.u;
}

// block-uniform dtype detect: sample x's first 4 KB; f32 buffers decode as huge/NaN bf16
__device__ __forceinline__ int detect_f32(const ushort* xu, int* shflag) {
  int t = threadIdx.x & 255;
  if (t == 0) *shflag = 0;
  __syncthreads();
  int local = 0;
#pragma unroll
  for (int i = 0; i < 4; ++i) {
    float v = bf2f(xu[(t * 4 + i) * 2]);
    if (!(fabsf(v) < 1e4f)) local = 1;
  }
  if (local) atomicOr(shflag, 1);
  __syncthreads();
  return *shflag;
}

// ---- prep: W transpose + biases + smoothed X (Xs[n] = sum_sh x[(n+sh)%1600], sh in
// {-4,-2,0,2,4}; canonical-bf16 values summed in f32, fragV's exact sum order) ----
__global__ void k_prep(const void* __restrict__ x, const void* __restrict__ Wq,
                       const void* __restrict__ bq, const void* __restrict__ Wk,
                       const void* __restrict__ bk, const void* __restrict__ Wv,
                       const void* __restrict__ bv, char* __restrict__ ws) {
  __shared__ int shflag;
  __shared__ ushort tileb[32][33];
  int isf32 = detect_f32((const ushort*)x, &shflag);
  int b = blockIdx.x, t = threadIdx.x;

  if (b < 192) {                       // W transpose: 64 32x32 tiles per z
    int z = b >> 6, tile = b & 63;
    const void* W = (z == 0) ? Wq : ((z == 1) ? Wk : Wv);
    int o0 = (tile & 7) * 32, k0 = (tile >> 3) * 32;
    int tx = t & 31, ty = t >> 5;
#pragma unroll
    for (int i = 0; i < 32; i += 8) {
      int kk = (k0 + ty + i) * 256 + o0 + tx;
      tileb[ty + i][tx] = isf32 ? f2bf(((const float*)W)[kk]) : ((const ushort*)W)[kk];
    }
    __syncthreads();
    ushort* WT = (ushort*)(ws + OFF_WT) + z * 65536;
#pragma unroll
    for (int i = 0; i < 32; i += 8)
      WT[(o0 + ty + i) * 256 + k0 + tx] = tileb[tx][ty + i];
  } else if (b == 192) {               // biases
    ushort* bb = (ushort*)(ws + OFF_BIAS);
#pragma unroll
    for (int z = 0; z < 3; ++z) {
      const void* B = (z == 0) ? bq : ((z == 1) ? bk : bv);
      bb[z * 256 + t] = isf32 ? f2bf(((const float*)B)[t]) : ((const ushort*)B)[t];
    }
  } else {                             // Xs: 200 blocks x 256 threads = 51200 chunks
    int jid = (b - 193) * 256 + t;     // chunk = 8 channels of one point
    int n = jid >> 5, ch0 = (jid & 31) * 8;
    int nm4 = n - 4 + ((n < 4) ? 1600 : 0);
    int nm2 = n - 2 + ((n < 2) ? 1600 : 0);
    int np2 = n + 2 - ((n >= 1598) ? 1600 : 0);
    int np4 = n + 4 - ((n >= 1596) ? 1600 : 0);
    int rows[5] = {nm4, nm2, n, np2, np4};
    union { ushort us[8]; bf16x8 v; } rv[5];
    if (isf32) {
      const float4* X4 = (const float4*)x;
#pragma unroll
      for (int r = 0; r < 5; ++r) {
        int i4 = (rows[r] * 256 + ch0) >> 2;
        float4 f0 = X4[i4], f1 = X4[i4 + 1];
        rv[r].us[0] = f2bf(f0.x); rv[r].us[1] = f2bf(f0.y);
        rv[r].us[2] = f2bf(f0.z); rv[r].us[3] = f2bf(f0.w);
        rv[r].us[4] = f2bf(f1.x); rv[r].us[5] = f2bf(f1.y);
        rv[r].us[6] = f2bf(f1.z); rv[r].us[7] = f2bf(f1.w);
      }
    } else {
      const ushort* Xu = (const ushort*)x;
#pragma unroll
      for (int r = 0; r < 5; ++r)
        rv[r].v = *(const bf16x8*)(Xu + rows[r] * 256 + ch0);
    }
    union { ushort us[8]; bf16x8 v; } o;
#pragma unroll
    for (int j = 0; j < 8; ++j) {
      float s = bf2f(rv[0].us[j]) + bf2f(rv[1].us[j]) + bf2f(rv[2].us[j]) +
                bf2f(rv[3].us[j]) + bf2f(rv[4].us[j]);
      o.us[j] = f2bf(s);
    }
    *(bf16x8*)((ushort*)(ws + OFF_XS) + n * 256 + ch0) = o.v;
  }
}

// -------- projections (R20): 1200 blocks x 256 threads, one (z, head, nb) job per
// block; 4 waves = 4 os column-quarters. 4x the TLP of R19 (proj was latency-bound
// at 1 block/CU) and 1/4 the per-wave chain: 8 MFMA + 16 loads. Same slot formulas
// and rounding paths as R19 (verified) -> bit-identical output.
__launch_bounds__(256)
__global__ void k_proj(const void* __restrict__ x, const ushort* __restrict__ WT,
                       const ushort* __restrict__ bias3, char* __restrict__ ws) {
  __shared__ int shflag;
  __shared__ ushort ktile[16][72];         // [point-local][d] (+8 pad)
  int isf32 = detect_f32((const ushort*)x, &shflag);
  int b = blockIdx.x;
  int z = b / 400, rem = b % 400;
  int head = rem / 100, nb = rem % 100;
  int n0 = nb * 16;
  const ushort* WTz = WT + z * 65536;
  const ushort* bias = bias3 + z * 256;
  int tid = threadIdx.x;
  int os = tid >> 6, lane = tid & 63;
  int c = lane & 15, quad = lane >> 4;

  f32x4 acc = (f32x4){0.f, 0.f, 0.f, 0.f};
  int ebase = (n0 + c) * 256;              // element index of this lane's input row
  const ushort* Xs = (const ushort*)(ws + OFF_XS);
  const ushort* wrow = WTz + (head * 64 + os * 16 + c) * 256;
#pragma unroll
  for (int kt = 0; kt < 8; ++kt) {
    bf16x8 a;
    if (z == 2) {
      a = *(const bf16x8*)(Xs + ebase + kt * 32 + quad * 8);
    } else if (isf32) {
      const float4* X4 = (const float4*)x;
      int i4 = (ebase + kt * 32 + quad * 8) >> 2;
      float4 f0 = X4[i4], f1 = X4[i4 + 1];
      union { ushort us[8]; bf16x8 v; } cv;
      cv.us[0] = f2bf(f0.x); cv.us[1] = f2bf(f0.y);
      cv.us[2] = f2bf(f0.z); cv.us[3] = f2bf(f0.w);
      cv.us[4] = f2bf(f1.x); cv.us[5] = f2bf(f1.y);
      cv.us[6] = f2bf(f1.z); cv.us[7] = f2bf(f1.w);
      a = cv.v;
    } else {
      a = *(const bf16x8*)((const ushort*)x + ebase + kt * 32 + quad * 8);
    }
    bf16x8 bfr = *(const bf16x8*)(wrow + kt * 32 + quad * 8);
    acc = __builtin_amdgcn_mfma_f32_16x16x32_bf16(a, bfr, acc, 0, 0, 0);
  }

  // fold 1/sqrt(256) AND log2(e) into Q (exp2 softmax); V bias x5 (S applied to X side)
  float scale = (z == 0) ? 0.0625f * 1.44269504088896f : 1.0f;
  float bmul = (z == 2) ? 5.f : 1.f;
  float bval = bf2f(bias[head * 64 + os * 16 + c]);
#pragma unroll
  for (int r = 0; r < 4; ++r)
    ktile[quad * 4 + r][os * 16 + c] = f2bf((acc[r] + bmul * bval) * scale);
  __syncthreads();

  if (z == 0) {
    // vectorized Q store: thread -> row kl = tid>>4, 4 channels at d4 = (tid&15)*4
    ushort* Qh = (ushort*)(ws + OFF_QH);
    int kl = tid >> 4, d4 = (tid & 15) * 4;
    ushort4 v = *(const ushort4*)&ktile[kl][d4];     // row stride 144B, d4*2 8B-aligned
    *(ushort4*)(Qh + (size_t)head * (N_PTS * HD) + (size_t)(n0 + kl) * HD + d4) = v;
  } else if (z == 1) {
    // DIRECT fragment-major K store (slot formulas verified R5-R7). Block covers keys
    // [t*32+hf*16, +16), t = nb>>1, hf = nb&1; this job owns cc in [hf*8, hf*8+8).
    if (tid < 128) {
      ushort* Kf = (ushort*)(ws + OFF_KF);
      int hf = nb & 1, t = nb >> 1;
      int quad_o = tid >> 5, ch = (tid >> 3) & 3, cc = (tid & 7) + hf * 8;
      int kl = ((cc >> 2) << 3) + (cc & 3) + ((ch >> 1) << 2) - hf * 16;
      int d0 = (ch & 1) * 32 + quad_o * 8;
      bf16x8 v = *(const bf16x8*)&ktile[kl][d0];     // 16B-aligned (144B rows)
      *(bf16x8*)(Kf + ((((size_t)head * 50 + t) * 4 + ch) * 64 + quad_o * 16 + cc) * 8) = v;
    }
  } else {
    // DIRECT fragment-major V store (verified R7). head == vg; covers quads 2*hf+{0,1}.
    if (tid < 128) {
      ushort* Vf = (ushort*)(ws + OFF_VF);
      int hf = nb & 1, t = nb >> 1;
      int ds = tid >> 5, qh = (tid >> 4) & 1, cc = tid & 15;
      union { ushort us[8]; bf16x8 v; } o;
#pragma unroll
      for (int j = 0; j < 8; ++j)
        o.us[j] = ktile[8 * qh + j][ds * 16 + cc];
      *(bf16x8*)(Vf + ((((size_t)head * 50 + t) * 4 + ds) * 64 + (2 * hf + qh) * 16 + cc) * 8) = o.v;
    }
  }
}

// exp2 + pack 8 scores into the 16x16x32 PV A-fragment (permuted-key trick, validated R9)
__device__ __forceinline__ bf16x8 pack_p8(const f32x4& s0, const f32x4& s1, float& lp) {
  float e0 = exp2f(s0[0]), e1 = exp2f(s0[1]), e2 = exp2f(s0[2]), e3 = exp2f(s0[3]);
  float e4 = exp2f(s1[0]), e5 = exp2f(s1[1]), e6 = exp2f(s1[2]), e7 = exp2f(s1[3]);
  lp += ((e0 + e1) + (e2 + e3)) + ((e4 + e5) + (e6 + e7));
  union { uint32_t u[4]; bf16x8 v; } r;
  r.u[0] = pk2(e0, e1); r.u[1] = pk2(e2, e3);
  r.u[2] = pk2(e4, e5); r.u[3] = pk2(e6, e7);
  return r.v;
}

#define MFMA16(a, b, cc) __builtin_amdgcn_mfma_f32_16x16x32_bf16(a, b, cc, 0, 0, 0)

// load one 4 KB K tile + 4 KB V tile into a named register buffer (A or B)
#define LOADT(sfx, t) do {                                            \
    const char* kt_ = kfp + (size_t)(t) * 4096;                       \
    const char* vt_ = vfp + (size_t)(t) * 4096;                       \
    ka0##sfx = *(const bf16x8*)(kt_);                                 \
    ka1##sfx = *(const bf16x8*)(kt_ + 1024);                          \
    kb0##sfx = *(const bf16x8*)(kt_ + 2048);                          \
    kb1##sfx = *(const bf16x8*)(kt_ + 3072);                          \
    vb0##sfx = *(const bf16x8*)(vt_);                                 \
    vb1##sfx = *(const bf16x8*)(vt_ + 1024);                          \
    vb2##sfx = *(const bf16x8*)(vt_ + 2048);                          \
    vb3##sfx = *(const bf16x8*)(vt_ + 3072);                          \
  } while (0)

// full 32-key x 16-query x 2-head tile: QK MFMAs -> exp2 pack -> PV MFMAs
#define COMPUTE(sfx) do {                                             \
    __builtin_amdgcn_s_setprio(1);                                    \
    f32x4 s0 = MFMA16(ka0##sfx, qa00, z4);                            \
    s0 = MFMA16(ka1##sfx, qa01, s0);                                  \
    f32x4 s1 = MFMA16(kb0##sfx, qa00, z4);                            \
    s1 = MFMA16(kb1##sfx, qa01, s1);                                  \
    bf16x8 pa0 = pack_p8(s0, s1, lp0);                                \
    oacc0[0] = MFMA16(pa0, vb0##sfx, oacc0[0]);                       \
    oacc0[1] = MFMA16(pa0, vb1##sfx, oacc0[1]);                       \
    oacc0[2] = MFMA16(pa0, vb2##sfx, oacc0[2]);                       \
    oacc0[3] = MFMA16(pa0, vb3##sfx, oacc0[3]);                       \
    s0 = MFMA16(ka0##sfx, qa10, z4);                                  \
    s0 = MFMA16(ka1##sfx, qa11, s0);                                  \
    s1 = MFMA16(kb0##sfx, qa10, z4);                                  \
    s1 = MFMA16(kb1##sfx, qa11, s1);                                  \
    bf16x8 pa1 = pack_p8(s0, s1, lp1);                                \
    oacc1[0] = MFMA16(pa1, vb0##sfx, oacc1[0]);                       \
    oacc1[1] = MFMA16(pa1, vb1##sfx, oacc1[1]);                       \
    oacc1[2] = MFMA16(pa1, vb2##sfx, oacc1[2]);                       \
    oacc1[3] = MFMA16(pa1, vb3##sfx, oacc1[3]);                       \
    __builtin_amdgcn_s_setprio(0);                                    \
  } while (0)

// ---- attention + final output. Grid (100 qt, 2 hp), 512 threads.
// 8 waves = 4 kg x 2 key-halves; each wave owns 25 of kg's 50 tiles. Cross-kg weighted
// reduction in LDS, final normalized output written directly (dtype-detected).
__launch_bounds__(512)
__global__ void k_attn(const ushort* __restrict__ Qh, const ushort* __restrict__ Kf,
                       const ushort* __restrict__ Vf, const void* __restrict__ x,
                       void* __restrict__ out) {
  __shared__ int shflag;
  __shared__ float obuf[8][16][68];   // [sp][q][d] f32 partials (epilogue only)
  __shared__ float lbuf[8][16];
  int isf32 = detect_f32((const ushort*)x, &shflag);

  int qt = blockIdx.x;
  int hp = blockIdx.y;           // query-head pair: handles hq = hp, hp+2
  int tid = threadIdx.x, sp = tid >> 6, lane = tid & 63;
  int kg = sp & 3, zh = sp >> 2; // key group + key half
  int vg = (2 * hp - kg + 8) & 3;
  int c = lane & 15, quad = lane >> 4;
  int n0 = qt * 16;

  const ushort* q0row = Qh + ((hp    ) * N_PTS + n0 + c) * HD;
  const ushort* q1row = Qh + ((hp + 2) * N_PTS + n0 + c) * HD;
  bf16x8 qa00 = *(const bf16x8*)(q0row + quad * 8);
  bf16x8 qa01 = *(const bf16x8*)(q0row + 32 + quad * 8);
  bf16x8 qa10 = *(const bf16x8*)(q1row + quad * 8);
  bf16x8 qa11 = *(const bf16x8*)(q1row + 32 + quad * 8);

  f32x4 oacc0[4], oacc1[4];
#pragma unroll
  for (int i = 0; i < 4; ++i) {
    oacc0[i] = (f32x4){0.f, 0.f, 0.f, 0.f};
    oacc1[i] = (f32x4){0.f, 0.f, 0.f, 0.f};
  }
  float lp0 = 0.f, lp1 = 0.f;

  int off = zh * 25;             // 25 tiles per key half
  const int iters = 25;
  const f32x4 z4 = (f32x4){0.f, 0.f, 0.f, 0.f};

  const char* kfp = (const char*)Kf + (size_t)(kg * 50 + off) * 4096 + lane * 16;
  const char* vfp = (const char*)Vf + (size_t)(vg * 50 + off) * 4096 + lane * 16;

  bf16x8 ka0A, ka1A, kb0A, kb1A, vb0A, vb1A, vb2A, vb3A;
  bf16x8 ka0B, ka1B, kb0B, kb1B, vb0B, vb1B, vb2B, vb3B;

  LOADT(A, 0);
  int it = 0;
  for (; it + 2 <= iters; it += 2) {
    LOADT(B, it + 1);                         // prefetch while computing A
    COMPUTE(A);
    int tn = (it + 2 < iters) ? (it + 2) : (it + 1);  // clamp: dup load, never OOB-used
    LOADT(A, tn);                             // prefetch while computing B
    COMPUTE(B);
  }
  if (it < iters) COMPUTE(A);                 // odd tail

  // per-wave L: lanes c, c+16, c+32, c+48 hold disjoint-key partials for q=c
  lp0 += __shfl_xor(lp0, 16, 64); lp0 += __shfl_xor(lp0, 32, 64);
  lp1 += __shfl_xor(lp1, 16, 64); lp1 += __shfl_xor(lp1, 32, 64);

  // O C-layout: oaccX[ds] reg r = O[q=quad*4+r][d=ds*16+c]; weighted cross-kg reduce
#pragma unroll
  for (int h = 0; h < 2; ++h) {
    __syncthreads();
    const f32x4* oa = h ? oacc1 : oacc0;
#pragma unroll
    for (int ds = 0; ds < 4; ++ds)
#pragma unroll
      for (int r = 0; r < 4; ++r)
        obuf[sp][quad * 4 + r][ds * 16 + c] = oa[ds][r];
    if (quad == 0) lbuf[sp][c] = h ? lp1 : lp0;
    __syncthreads();

    int q = tid >> 5, dp = (tid & 31) * 2;   // 16 q x 32 d-pairs = 512 threads
    int hq = hp + 2 * h;
    float a0 = 0.f, a1 = 0.f;
#pragma unroll
    for (int g = 0; g < 4; ++g) {
      float n0v = obuf[g][q][dp]     + obuf[g + 4][q][dp];
      float n1v = obuf[g][q][dp + 1] + obuf[g + 4][q][dp + 1];
      float l   = lbuf[g][q] + lbuf[g + 4][q];
      float w   = (g == ((hq + 2) & 3)) ? 2.f : 1.f;
      float rl  = w / l;
      a0 += n0v * rl; a1 += n1v * rl;
    }
    size_t oidx = (size_t)(n0 + q) * 256 + hq * 64 + dp;
    if (isf32) {
      ((float2*)out)[oidx >> 1] = make_float2(a0, a1);
    } else {
      ((uint32_t*)out)[oidx >> 1] = pk2(a0, a1);
    }
  }
}

extern "C" void kernel_launch(void* const* d_in, const int* in_sizes, int n_in,
                              void* d_out, int out_size, void* d_ws, size_t ws_size,
                              hipStream_t stream) {
  char* ws = (char*)d_ws;
  ushort* WT    = (ushort*)(ws + OFF_WT);
  ushort* bias3 = (ushort*)(ws + OFF_BIAS);
  ushort* Qh    = (ushort*)(ws + OFF_QH);
  ushort* Kf    = (ushort*)(ws + OFF_KF);
  ushort* Vf    = (ushort*)(ws + OFF_VF);

  k_prep<<<393, 256, 0, stream>>>(d_in[0], d_in[1], d_in[2], d_in[3],
                                  d_in[4], d_in[5], d_in[6], ws);
  k_proj<<<1200, 256, 0, stream>>>(d_in[0], WT, bias3, ws);
  k_attn<<<dim3(100, 2), 512, 0, stream>>>(Qh, Kf, Vf, d_in[0], d_out);
}

// Round 9
// 105.833 us; speedup vs baseline: 1.0352x; 1.0352x over previous
//
#include <hip/hip_runtime.h>
#include <hip/hip_bf16.h>
#include <stdint.h>

typedef __attribute__((ext_vector_type(8))) __bf16 bf16x8;
typedef __attribute__((ext_vector_type(4))) float f32x4;

#define N_PTS 1600
#define HD    64

// ---- ws layout (bytes). R21 == R19 (best measured: 107.2us). 3-kernel chain,
// smooth-X before proj (linear: S(XW+b) = (SX)W + 5b). R20's 4x-TLP proj split
// measured neutral-to-negative -> reverted.
#define OFF_WT   0u          //  393216 : 3 x [256][256] bf16 W^T
#define OFF_BIAS 393216u     //    1536 : 3 x 256 bf16
#define OFF_XS   394752u     //  819200 : [1600][256] bf16 smoothed canonical x
#define OFF_QH   1213952u    //  819200 : [4][1600][64] bf16 Q (live through attn)
#define OFF_KF   2033152u    //  819200 : fragment-major K  [kg][50 t][4 ch][64 lane][8]
#define OFF_VF   2852352u    //  819200 : fragment-major smoothed V [vg][50 t][4 ds][64 lane][8]

__device__ __forceinline__ float bf2f(ushort h) {
  union { uint32_t u; float f; } v; v.u = ((uint32_t)h) << 16; return v.f;
}
__device__ __forceinline__ ushort f2bf(float f) {
  union { float f; uint32_t u; } v; v.f = f;
  uint32_t u = v.u;
  return (ushort)((u + 0x7FFFu + ((u >> 16) & 1u)) >> 16);
}
__device__ __forceinline__ uint32_t pk2(float a, float b) {
  union { __hip_bfloat162 h; uint32_t u; } cv;
  cv.h = __float22bfloat162_rn(make_float2(a, b));
  return cv.u;
}

// block-uniform dtype detect: sample x's first 4 KB; f32 buffers decode as huge/NaN bf16
__device__ __forceinline__ int detect_f32(const ushort* xu, int* shflag) {
  int t = threadIdx.x & 255;
  if (t == 0) *shflag = 0;
  __syncthreads();
  int local = 0;
#pragma unroll
  for (int i = 0; i < 4; ++i) {
    float v = bf2f(xu[(t * 4 + i) * 2]);
    if (!(fabsf(v) < 1e4f)) local = 1;
  }
  if (local) atomicOr(shflag, 1);
  __syncthreads();
  return *shflag;
}

// ---- prep: W transpose + biases + smoothed X (Xs[n] = sum_sh x[(n+sh)%1600], sh in
// {-4,-2,0,2,4}; canonical-bf16 values summed in f32, fragV's exact sum order) ----
__global__ void k_prep(const void* __restrict__ x, const void* __restrict__ Wq,
                       const void* __restrict__ bq, const void* __restrict__ Wk,
                       const void* __restrict__ bk, const void* __restrict__ Wv,
                       const void* __restrict__ bv, char* __restrict__ ws) {
  __shared__ int shflag;
  __shared__ ushort tileb[32][33];
  int isf32 = detect_f32((const ushort*)x, &shflag);
  int b = blockIdx.x, t = threadIdx.x;

  if (b < 192) {                       // W transpose: 64 32x32 tiles per z
    int z = b >> 6, tile = b & 63;
    const void* W = (z == 0) ? Wq : ((z == 1) ? Wk : Wv);
    int o0 = (tile & 7) * 32, k0 = (tile >> 3) * 32;
    int tx = t & 31, ty = t >> 5;
#pragma unroll
    for (int i = 0; i < 32; i += 8) {
      int kk = (k0 + ty + i) * 256 + o0 + tx;
      tileb[ty + i][tx] = isf32 ? f2bf(((const float*)W)[kk]) : ((const ushort*)W)[kk];
    }
    __syncthreads();
    ushort* WT = (ushort*)(ws + OFF_WT) + z * 65536;
#pragma unroll
    for (int i = 0; i < 32; i += 8)
      WT[(o0 + ty + i) * 256 + k0 + tx] = tileb[tx][ty + i];
  } else if (b == 192) {               // biases
    ushort* bb = (ushort*)(ws + OFF_BIAS);
#pragma unroll
    for (int z = 0; z < 3; ++z) {
      const void* B = (z == 0) ? bq : ((z == 1) ? bk : bv);
      bb[z * 256 + t] = isf32 ? f2bf(((const float*)B)[t]) : ((const ushort*)B)[t];
    }
  } else {                             // Xs: 200 blocks x 256 threads = 51200 chunks
    int jid = (b - 193) * 256 + t;     // chunk = 8 channels of one point
    int n = jid >> 5, ch0 = (jid & 31) * 8;
    int nm4 = n - 4 + ((n < 4) ? 1600 : 0);
    int nm2 = n - 2 + ((n < 2) ? 1600 : 0);
    int np2 = n + 2 - ((n >= 1598) ? 1600 : 0);
    int np4 = n + 4 - ((n >= 1596) ? 1600 : 0);
    int rows[5] = {nm4, nm2, n, np2, np4};
    union { ushort us[8]; bf16x8 v; } rv[5];
    if (isf32) {
      const float4* X4 = (const float4*)x;
#pragma unroll
      for (int r = 0; r < 5; ++r) {
        int i4 = (rows[r] * 256 + ch0) >> 2;
        float4 f0 = X4[i4], f1 = X4[i4 + 1];
        rv[r].us[0] = f2bf(f0.x); rv[r].us[1] = f2bf(f0.y);
        rv[r].us[2] = f2bf(f0.z); rv[r].us[3] = f2bf(f0.w);
        rv[r].us[4] = f2bf(f1.x); rv[r].us[5] = f2bf(f1.y);
        rv[r].us[6] = f2bf(f1.z); rv[r].us[7] = f2bf(f1.w);
      }
    } else {
      const ushort* Xu = (const ushort*)x;
#pragma unroll
      for (int r = 0; r < 5; ++r)
        rv[r].v = *(const bf16x8*)(Xu + rows[r] * 256 + ch0);
    }
    union { ushort us[8]; bf16x8 v; } o;
#pragma unroll
    for (int j = 0; j < 8; ++j) {
      float s = bf2f(rv[0].us[j]) + bf2f(rv[1].us[j]) + bf2f(rv[2].us[j]) +
                bf2f(rv[3].us[j]) + bf2f(rv[4].us[j]);
      o.us[j] = f2bf(s);
    }
    *(bf16x8*)((ushort*)(ws + OFF_XS) + n * 256 + ch0) = o.v;
  }
}

// -------- projections: 150 blocks x 512 threads = 2 jobs/block, 300 jobs total.
// job<100: z=0 (Q), 100..199: z=1 (K -> Kf DIRECT), 200..299: z=2 (Xs -> Vf DIRECT).
// WT vectorized loads; x raw (dtype-branched) for Q/K, Xs (bf16) for V.
// All epilogues bounce through LDS ktile for vectorized / fragment-major stores.
__launch_bounds__(512)
__global__ void k_proj(const void* __restrict__ x, const ushort* __restrict__ WT,
                       const ushort* __restrict__ bias3, char* __restrict__ ws) {
  __shared__ int shflag;
  __shared__ ushort ktile[2][4][16][72];   // [jobhalf][head][point-local][d] (+8 pad)
  int isf32 = detect_f32((const ushort*)x, &shflag);
  int tid = threadIdx.x;
  int half = tid >> 8;
  int job = blockIdx.x + 150 * half;       // b<150 -> jobs b and b+150
  int z = job / 100, nb = job % 100;
  int n0 = nb * 16;
  const ushort* WTz = WT + z * 65536;
  const ushort* bias = bias3 + z * 256;
  int t256 = tid & 255;
  int head = t256 >> 6, lane = t256 & 63;
  int c = lane & 15, quad = lane >> 4;

  f32x4 acc[4];
#pragma unroll
  for (int i = 0; i < 4; ++i) acc[i] = (f32x4){0.f, 0.f, 0.f, 0.f};

  int ebase = (n0 + c) * 256;              // element index of this lane's input row
  const ushort* Xs = (const ushort*)(ws + OFF_XS);
#pragma unroll
  for (int kt = 0; kt < 8; ++kt) {
    bf16x8 a;
    if (z == 2) {
      a = *(const bf16x8*)(Xs + ebase + kt * 32 + quad * 8);
    } else if (isf32) {
      const float4* X4 = (const float4*)x;
      int i4 = (ebase + kt * 32 + quad * 8) >> 2;
      float4 f0 = X4[i4], f1 = X4[i4 + 1];
      union { ushort us[8]; bf16x8 v; } cv;
      cv.us[0] = f2bf(f0.x); cv.us[1] = f2bf(f0.y);
      cv.us[2] = f2bf(f0.z); cv.us[3] = f2bf(f0.w);
      cv.us[4] = f2bf(f1.x); cv.us[5] = f2bf(f1.y);
      cv.us[6] = f2bf(f1.z); cv.us[7] = f2bf(f1.w);
      a = cv.v;
    } else {
      a = *(const bf16x8*)((const ushort*)x + ebase + kt * 32 + quad * 8);
    }
#pragma unroll
    for (int os = 0; os < 4; ++os) {
      bf16x8 bfr = *(const bf16x8*)(WTz + (head * 64 + os * 16 + c) * 256 + kt * 32 + quad * 8);
      acc[os] = __builtin_amdgcn_mfma_f32_16x16x32_bf16(a, bfr, acc[os], 0, 0, 0);
    }
  }

  // fold 1/sqrt(256) AND log2(e) into Q (exp2 softmax); V bias x5 (S applied to X side)
  float scale = (z == 0) ? 0.0625f * 1.44269504088896f : 1.0f;
  float bmul = (z == 2) ? 5.f : 1.f;
#pragma unroll
  for (int os = 0; os < 4; ++os) {
    float bval = bf2f(bias[head * 64 + os * 16 + c]);
#pragma unroll
    for (int r = 0; r < 4; ++r)
      ktile[half][head][quad * 4 + r][os * 16 + c] =
          f2bf((acc[os][r] + bmul * bval) * scale);
  }
  __syncthreads();

  if (z == 0) {
    // vectorized Q store: lane -> row kl = lane>>2, d0 = (lane&3)*16; 2x 16B
    ushort* Qh = (ushort*)(ws + OFF_QH);
    int kl = lane >> 2, d0 = (lane & 3) * 16;
    bf16x8 v0 = *(const bf16x8*)&ktile[half][head][kl][d0];
    bf16x8 v1 = *(const bf16x8*)&ktile[half][head][kl][d0 + 8];
    ushort* qrow = Qh + (size_t)head * (N_PTS * HD) + (size_t)(n0 + kl) * HD + d0;
    *(bf16x8*)qrow = v0;
    *(bf16x8*)(qrow + 8) = v1;
  } else if (z == 1) {
    // DIRECT fragment-major K store (verified R5). Block covers keys [t*32+hf*16, +16),
    // t = nb>>1, hf = nb&1. Fragment slot (t,ch,lane_o=(quad_o,cc)) holds
    // K[key = t*32 + perm(cc) + ((ch>>1)<<2)][d0 = (ch&1)*32 + quad_o*8 .. +7],
    // perm(cc) = ((cc>>2)<<3)+(cc&3). This block owns cc in [hf*8, hf*8+8).
    ushort* Kf = (ushort*)(ws + OFF_KF);
    int hf = nb & 1, t = nb >> 1;
    int quad_o = lane >> 4, chp = (lane >> 3) & 1, cc = (lane & 7) + hf * 8;
#pragma unroll
    for (int e = 0; e < 2; ++e) {
      int ch = chp + 2 * e;
      int kl = ((cc >> 2) << 3) + (cc & 3) + ((ch >> 1) << 2) - hf * 16;
      int d0 = (ch & 1) * 32 + quad_o * 8;
      bf16x8 v = *(const bf16x8*)&ktile[half][head][kl][d0];
      *(bf16x8*)(Kf + ((((size_t)head * 50 + t) * 4 + ch) * 64 + quad_o * 16 + cc) * 8) = v;
    }
  } else {
    // DIRECT fragment-major V store (verified R7). Vf[vg][t][ds][(quad',cc)][j] =
    // Vs[d=ds*16+cc][m = t*32 + quad'*8 + j]; this job covers m in [t*32+hf*16, +16)
    // -> quads quad' = 2*hf + qh, local row = 8*qh + j. head == vg.
    ushort* Vf = (ushort*)(ws + OFF_VF);
    int hf = nb & 1, t = nb >> 1;
    int cc = lane & 15, qh = (lane >> 4) & 1, dsp = lane >> 5;
#pragma unroll
    for (int e = 0; e < 2; ++e) {
      int ds = dsp * 2 + e;
      union { ushort us[8]; bf16x8 v; } o;
#pragma unroll
      for (int j = 0; j < 8; ++j)
        o.us[j] = ktile[half][head][8 * qh + j][ds * 16 + cc];
      *(bf16x8*)(Vf + ((((size_t)head * 50 + t) * 4 + ds) * 64 + (2 * hf + qh) * 16 + cc) * 8) = o.v;
    }
  }
}

// exp2 + pack 8 scores into the 16x16x32 PV A-fragment (permuted-key trick, validated R9)
__device__ __forceinline__ bf16x8 pack_p8(const f32x4& s0, const f32x4& s1, float& lp) {
  float e0 = exp2f(s0[0]), e1 = exp2f(s0[1]), e2 = exp2f(s0[2]), e3 = exp2f(s0[3]);
  float e4 = exp2f(s1[0]), e5 = exp2f(s1[1]), e6 = exp2f(s1[2]), e7 = exp2f(s1[3]);
  lp += ((e0 + e1) + (e2 + e3)) + ((e4 + e5) + (e6 + e7));
  union { uint32_t u[4]; bf16x8 v; } r;
  r.u[0] = pk2(e0, e1); r.u[1] = pk2(e2, e3);
  r.u[2] = pk2(e4, e5); r.u[3] = pk2(e6, e7);
  return r.v;
}

#define MFMA16(a, b, cc) __builtin_amdgcn_mfma_f32_16x16x32_bf16(a, b, cc, 0, 0, 0)

// load one 4 KB K tile + 4 KB V tile into a named register buffer (A or B)
#define LOADT(sfx, t) do {                                            \
    const char* kt_ = kfp + (size_t)(t) * 4096;                       \
    const char* vt_ = vfp + (size_t)(t) * 4096;                       \
    ka0##sfx = *(const bf16x8*)(kt_);                                 \
    ka1##sfx = *(const bf16x8*)(kt_ + 1024);                          \
    kb0##sfx = *(const bf16x8*)(kt_ + 2048);                          \
    kb1##sfx = *(const bf16x8*)(kt_ + 3072);                          \
    vb0##sfx = *(const bf16x8*)(vt_);                                 \
    vb1##sfx = *(const bf16x8*)(vt_ + 1024);                          \
    vb2##sfx = *(const bf16x8*)(vt_ + 2048);                          \
    vb3##sfx = *(const bf16x8*)(vt_ + 3072);                          \
  } while (0)

// full 32-key x 16-query x 2-head tile: QK MFMAs -> exp2 pack -> PV MFMAs
#define COMPUTE(sfx) do {                                             \
    __builtin_amdgcn_s_setprio(1);                                    \
    f32x4 s0 = MFMA16(ka0##sfx, qa00, z4);                            \
    s0 = MFMA16(ka1##sfx, qa01, s0);                                  \
    f32x4 s1 = MFMA16(kb0##sfx, qa00, z4);                            \
    s1 = MFMA16(kb1##sfx, qa01, s1);                                  \
    bf16x8 pa0 = pack_p8(s0, s1, lp0);                                \
    oacc0[0] = MFMA16(pa0, vb0##sfx, oacc0[0]);                       \
    oacc0[1] = MFMA16(pa0, vb1##sfx, oacc0[1]);                       \
    oacc0[2] = MFMA16(pa0, vb2##sfx, oacc0[2]);                       \
    oacc0[3] = MFMA16(pa0, vb3##sfx, oacc0[3]);                       \
    s0 = MFMA16(ka0##sfx, qa10, z4);                                  \
    s0 = MFMA16(ka1##sfx, qa11, s0);                                  \
    s1 = MFMA16(kb0##sfx, qa10, z4);                                  \
    s1 = MFMA16(kb1##sfx, qa11, s1);                                  \
    bf16x8 pa1 = pack_p8(s0, s1, lp1);                                \
    oacc1[0] = MFMA16(pa1, vb0##sfx, oacc1[0]);                       \
    oacc1[1] = MFMA16(pa1, vb1##sfx, oacc1[1]);                       \
    oacc1[2] = MFMA16(pa1, vb2##sfx, oacc1[2]);                       \
    oacc1[3] = MFMA16(pa1, vb3##sfx, oacc1[3]);                       \
    __builtin_amdgcn_s_setprio(0);                                    \
  } while (0)

// ---- attention + final output. Grid (100 qt, 2 hp), 512 threads.
// 8 waves = 4 kg x 2 key-halves; each wave owns 25 of kg's 50 tiles. Cross-kg weighted
// reduction in LDS, final normalized output written directly (dtype-detected).
__launch_bounds__(512)
__global__ void k_attn(const ushort* __restrict__ Qh, const ushort* __restrict__ Kf,
                       const ushort* __restrict__ Vf, const void* __restrict__ x,
                       void* __restrict__ out) {
  __shared__ int shflag;
  __shared__ float obuf[8][16][68];   // [sp][q][d] f32 partials (epilogue only)
  __shared__ float lbuf[8][16];
  int isf32 = detect_f32((const ushort*)x, &shflag);

  int qt = blockIdx.x;
  int hp = blockIdx.y;           // query-head pair: handles hq = hp, hp+2
  int tid = threadIdx.x, sp = tid >> 6, lane = tid & 63;
  int kg = sp & 3, zh = sp >> 2; // key group + key half
  int vg = (2 * hp - kg + 8) & 3;
  int c = lane & 15, quad = lane >> 4;
  int n0 = qt * 16;

  const ushort* q0row = Qh + ((hp    ) * N_PTS + n0 + c) * HD;
  const ushort* q1row = Qh + ((hp + 2) * N_PTS + n0 + c) * HD;
  bf16x8 qa00 = *(const bf16x8*)(q0row + quad * 8);
  bf16x8 qa01 = *(const bf16x8*)(q0row + 32 + quad * 8);
  bf16x8 qa10 = *(const bf16x8*)(q1row + quad * 8);
  bf16x8 qa11 = *(const bf16x8*)(q1row + 32 + quad * 8);

  f32x4 oacc0[4], oacc1[4];
#pragma unroll
  for (int i = 0; i < 4; ++i) {
    oacc0[i] = (f32x4){0.f, 0.f, 0.f, 0.f};
    oacc1[i] = (f32x4){0.f, 0.f, 0.f, 0.f};
  }
  float lp0 = 0.f, lp1 = 0.f;

  int off = zh * 25;             // 25 tiles per key half
  const int iters = 25;
  const f32x4 z4 = (f32x4){0.f, 0.f, 0.f, 0.f};

  const char* kfp = (const char*)Kf + (size_t)(kg * 50 + off) * 4096 + lane * 16;
  const char* vfp = (const char*)Vf + (size_t)(vg * 50 + off) * 4096 + lane * 16;

  bf16x8 ka0A, ka1A, kb0A, kb1A, vb0A, vb1A, vb2A, vb3A;
  bf16x8 ka0B, ka1B, kb0B, kb1B, vb0B, vb1B, vb2B, vb3B;

  LOADT(A, 0);
  int it = 0;
  for (; it + 2 <= iters; it += 2) {
    LOADT(B, it + 1);                         // prefetch while computing A
    COMPUTE(A);
    int tn = (it + 2 < iters) ? (it + 2) : (it + 1);  // clamp: dup load, never OOB-used
    LOADT(A, tn);                             // prefetch while computing B
    COMPUTE(B);
  }
  if (it < iters) COMPUTE(A);                 // odd tail

  // per-wave L: lanes c, c+16, c+32, c+48 hold disjoint-key partials for q=c
  lp0 += __shfl_xor(lp0, 16, 64); lp0 += __shfl_xor(lp0, 32, 64);
  lp1 += __shfl_xor(lp1, 16, 64); lp1 += __shfl_xor(lp1, 32, 64);

  // O C-layout: oaccX[ds] reg r = O[q=quad*4+r][d=ds*16+c]; weighted cross-kg reduce
#pragma unroll
  for (int h = 0; h < 2; ++h) {
    __syncthreads();
    const f32x4* oa = h ? oacc1 : oacc0;
#pragma unroll
    for (int ds = 0; ds < 4; ++ds)
#pragma unroll
      for (int r = 0; r < 4; ++r)
        obuf[sp][quad * 4 + r][ds * 16 + c] = oa[ds][r];
    if (quad == 0) lbuf[sp][c] = h ? lp1 : lp0;
    __syncthreads();

    int q = tid >> 5, dp = (tid & 31) * 2;   // 16 q x 32 d-pairs = 512 threads
    int hq = hp + 2 * h;
    float a0 = 0.f, a1 = 0.f;
#pragma unroll
    for (int g = 0; g < 4; ++g) {
      float n0v = obuf[g][q][dp]     + obuf[g + 4][q][dp];
      float n1v = obuf[g][q][dp + 1] + obuf[g + 4][q][dp + 1];
      float l   = lbuf[g][q] + lbuf[g + 4][q];
      float w   = (g == ((hq + 2) & 3)) ? 2.f : 1.f;
      float rl  = w / l;
      a0 += n0v * rl; a1 += n1v * rl;
    }
    size_t oidx = (size_t)(n0 + q) * 256 + hq * 64 + dp;
    if (isf32) {
      ((float2*)out)[oidx >> 1] = make_float2(a0, a1);
    } else {
      ((uint32_t*)out)[oidx >> 1] = pk2(a0, a1);
    }
  }
}

extern "C" void kernel_launch(void* const* d_in, const int* in_sizes, int n_in,
                              void* d_out, int out_size, void* d_ws, size_t ws_size,
                              hipStream_t stream) {
  char* ws = (char*)d_ws;
  ushort* WT    = (ushort*)(ws + OFF_WT);
  ushort* bias3 = (ushort*)(ws + OFF_BIAS);
  ushort* Qh    = (ushort*)(ws + OFF_QH);
  ushort* Kf    = (ushort*)(ws + OFF_KF);
  ushort* Vf    = (ushort*)(ws + OFF_VF);

  k_prep<<<393, 256, 0, stream>>>(d_in[0], d_in[1], d_in[2], d_in[3],
                                  d_in[4], d_in[5], d_in[6], ws);
  k_proj<<<150, 512, 0, stream>>>(d_in[0], WT, bias3, ws);
  k_attn<<<dim3(100, 2), 512, 0, stream>>>(Qh, Kf, Vf, d_in[0], d_out);
}